// Round 4
// baseline (700.399 us; speedup 1.0000x reference)
//
#include <hip/hip_runtime.h>
#include <hip/hip_bf16.h>
#include <math.h>

// B=4, S=2048, D=256, H=4, HD=64; keep top-10% per score row.
// thr = v205 + 0.3*(v204 - v205)  (v_k = (k+1)-th largest)

typedef __attribute__((ext_vector_type(8))) short short8;
typedef __attribute__((ext_vector_type(4))) short short4v;
typedef __attribute__((ext_vector_type(8))) _Float16 half8;
typedef __attribute__((ext_vector_type(4))) float floatx4;
typedef unsigned short ushort_t;

#define MFMA_BF(a,b,c)  __builtin_amdgcn_mfma_f32_16x16x32_bf16(a,b,c,0,0,0)
#define MFMA_F16(a,b,c) __builtin_amdgcn_mfma_f32_16x16x32_f16(a,b,c,0,0,0)

#define TBS 520   // u16/f16 elems per shared row (16B-aligned rows, bank-shift 4)

// ---------- helpers ----------
__device__ __forceinline__ unsigned mtu(float f){
  unsigned u = __float_as_uint(f);
  return (u & 0x80000000u) ? ~u : (u | 0x80000000u);
}
__device__ __forceinline__ float umt(unsigned u){
  return __uint_as_float((u & 0x80000000u) ? (u & 0x7fffffffu) : ~u);
}
__device__ __forceinline__ int wsum_i(int v){
  #pragma unroll
  for (int m=1;m<64;m<<=1) v += __shfl_xor(v,m,64);
  return v;
}
__device__ __forceinline__ ushort_t f2bf(float f){       // RNE f32->bf16
  unsigned u = __float_as_uint(f);
  return (ushort_t)((u + 0x7fffu + ((u>>16)&1u)) >> 16);
}
__device__ __forceinline__ float bf2f(ushort_t u){
  return __uint_as_float(((unsigned)u) << 16);
}
__device__ __forceinline__ short8 ldb8(const ushort_t* p){ return *(const short8*)p; }

// identical score computation in every pass (bit-exact across passes)
__device__ __forceinline__ void score_chunk(
    const ushort_t* __restrict__ Khb, const ushort_t* __restrict__ Klb,
    int base, int lk,
    short8 ah0, short8 ah1, short8 al0, short8 al1, floatx4 acc[4]){
  #pragma unroll
  for (int tl=0;tl<4;tl++){
    const size_t ko = (size_t)(base + tl*16)*64 + lk;
    short8 bh0 = ldb8(Khb + ko);
    short8 bh1 = ldb8(Khb + ko + 32);
    short8 bl0 = ldb8(Klb + ko);
    short8 bl1 = ldb8(Klb + ko + 32);
    floatx4 a = {0.f,0.f,0.f,0.f};
    a = MFMA_BF(ah0,bh0,a); a = MFMA_BF(ah1,bh1,a);
    a = MFMA_BF(al0,bh0,a); a = MFMA_BF(al1,bh1,a);
    a = MFMA_BF(ah0,bl0,a); a = MFMA_BF(ah1,bl1,a);
    a = MFMA_BF(al0,bl0,a); a = MFMA_BF(al1,bl1,a);
    acc[tl] = a;
  }
}

// ---------- K0: fp32 -> bf16 hi/lo for W(q|k|v) only (x split in-register) ----------
__global__ void cvt_w_kernel(const float* __restrict__ Wq, const float* __restrict__ Wk,
                             const float* __restrict__ Wv,
                             ushort_t* __restrict__ wh, ushort_t* __restrict__ wl){
  const int i = blockIdx.x*256 + threadIdx.x;       // 49152 float4s
  const size_t base = (size_t)i*4;
  const int row = i >> 6;                            // row 0..767
  const float* src = row<256 ? &Wq[base] : (row<512 ? &Wk[base-65536] : &Wv[base-131072]);
  float4 v = *(const float4*)src;
  short4v hv, lv; ushort_t h;
  h=f2bf(v.x); hv.x=(short)h; lv.x=(short)f2bf(v.x-bf2f(h));
  h=f2bf(v.y); hv.y=(short)h; lv.y=(short)f2bf(v.y-bf2f(h));
  h=f2bf(v.z); hv.z=(short)h; lv.z=(short)f2bf(v.z-bf2f(h));
  h=f2bf(v.w); hv.w=(short)h; lv.w=(short)f2bf(v.w-bf2f(h));
  *(short4v*)&wh[base] = hv;
  *(short4v*)&wl[base] = lv;
}

// ---------- K1a: per-(b,chunk) column sums of x ----------
__global__ void xpart_kernel(const float* __restrict__ x, float* __restrict__ xpart){
  const int ch = blockIdx.x, b = blockIdx.y, t = threadIdx.x;
  const float* xp = x + ((size_t)b*2048 + (size_t)ch*128)*256 + t;
  float s = 0.f;
  for (int i=0;i<128;i++) s += xp[(size_t)i*256];
  xpart[(size_t)(b*16+ch)*256 + t] = s;
}

// ---------- K1b: gate + fold distill/gate/out into M_b (coalesced stores) ----------
__global__ void gate_mprep_kernel(const float* __restrict__ xpart,
    const float* __restrict__ Wg, const float* __restrict__ bg,
    const float* __restrict__ Wgp,const float* __restrict__ bgp,
    const float* __restrict__ Wd, const float* __restrict__ bd,
    const float* __restrict__ Wo, const float* __restrict__ bo,
    ushort_t* __restrict__ mt_h, ushort_t* __restrict__ mt_l,
    float* __restrict__ bo_b){
  __shared__ float xm[256];
  __shared__ float g16[16];
  __shared__ float gs[256];
  __shared__ float coef[256];
  const int b = blockIdx.x, t = threadIdx.x;
  float s = 0.f;
  for (int ch=0; ch<16; ch++) s += xpart[(size_t)(b*16+ch)*256 + t];
  xm[t] = s * (1.0f/2048.0f);
  __syncthreads();
  if (t < 16){
    float z = bg[t];
    for (int d=0; d<256; d++) z = fmaf(xm[d], Wg[t*256+d], z);
    g16[t] = 1.0f/(1.0f + __expf(-z));
  }
  __syncthreads();
  float z2 = bgp[t];
  #pragma unroll
  for (int j=0;j<16;j++) z2 = fmaf(g16[j], Wgp[t*16+j], z2);
  gs[t] = z2;
  coef[t] = z2 * bd[t&15];
  __syncthreads();
  // M: thread owns column k=t; loop over output rows j (stores coalesced over t)
  float e[16];
  const int g0 = t & ~15, klo = t & 15;
  #pragma unroll
  for (int m=0;m<16;m++) e[m] = gs[g0+m] * Wd[m*16 + klo];
  const float omg = 1.0f - gs[t];
  for (int j=0;j<256;j++){
    const float* wor = Wo + (size_t)j*256;
    float acc = omg * wor[t];
    #pragma unroll
    for (int m=0;m<16;m++) acc = fmaf(e[m], wor[g0+m], acc);
    const ushort_t hi = f2bf(acc);
    mt_h[((size_t)b*256 + j)*256 + t] = hi;
    mt_l[((size_t)b*256 + j)*256 + t] = f2bf(acc - bf2f(hi));
  }
  float bacc = bo[t];
  const float* worT = Wo + (size_t)t*256;
  for (int i=0;i<256;i++) bacc = fmaf(coef[i], worT[i], bacc);
  bo_b[b*256 + t] = bacc;
}

// ---------- K2: QKV projection, split-bf16 MFMA; x split in-register ----------
__global__ __launch_bounds__(256) void qkv_mfma(
    const float* __restrict__ x,
    const ushort_t* __restrict__ wh, const ushort_t* __restrict__ wl,
    const float* __restrict__ bq, const float* __restrict__ bk, const float* __restrict__ bv,
    ushort_t* __restrict__ qh, ushort_t* __restrict__ ql,
    ushort_t* __restrict__ kh, ushort_t* __restrict__ kl,
    _Float16* __restrict__ vt){
  __shared__ unsigned stage[64][68];                 // 17.4 KB (reused as f16 for V)
  const int m0 = blockIdx.x*64, n0g = blockIdx.y*64;
  const int sect = n0g >> 8, nloc0 = n0g & 255;
  const int tid = threadIdx.x, w = tid>>6, ln = tid&63;
  const int lm = ln&15, quad = ln>>4, lk = quad*8;
  const int arow = m0 + w*16 + lm;

  floatx4 acc[4];
  #pragma unroll
  for (int nt=0;nt<4;nt++){ floatx4 z = {0.f,0.f,0.f,0.f}; acc[nt] = z; }

  for (int k0=0;k0<256;k0+=32){
    const float* xp = &x[(size_t)arow*256 + k0 + lk];
    float4 xa = *(const float4*)xp;
    float4 xb = *(const float4*)(xp+4);
    float xv[8] = {xa.x,xa.y,xa.z,xa.w,xb.x,xb.y,xb.z,xb.w};
    short8 a_h, a_l;
    #pragma unroll
    for (int j=0;j<8;j++){
      const ushort_t h = f2bf(xv[j]);
      a_h[j] = (short)h;
      a_l[j] = (short)f2bf(xv[j] - bf2f(h));
    }
    #pragma unroll
    for (int nt=0;nt<4;nt++){
      const size_t boff = (size_t)(n0g + nt*16 + lm)*256 + k0 + lk;
      short8 b_h = ldb8(&wh[boff]);
      short8 b_l = ldb8(&wl[boff]);
      acc[nt] = MFMA_BF(a_h,b_h,acc[nt]);
      acc[nt] = MFMA_BF(a_h,b_l,acc[nt]);
      acc[nt] = MFMA_BF(a_l,b_h,acc[nt]);
      acc[nt] = MFMA_BF(a_l,b_l,acc[nt]);
    }
  }

  const float* bias = (sect==0)?bq:((sect==1)?bk:bv);
  const int bidx = m0 >> 11, hh = nloc0 >> 6;
  if (sect < 2){
    #pragma unroll
    for (int nt=0;nt<4;nt++){
      #pragma unroll
      for (int r=0;r<4;r++){
        const int m = w*16 + quad*4 + r;
        const int f = nt*16 + lm;
        const float val = acc[nt][r] + bias[nloc0 + f];
        const ushort_t hi = f2bf(val);
        const ushort_t lo = f2bf(val - bf2f(hi));
        stage[m][f] = (unsigned)hi | ((unsigned)lo << 16);
      }
    }
    __syncthreads();
    const int mrow = tid>>2, seg = (tid&3)*16;
    unsigned pk[16];
    #pragma unroll
    for (int j=0;j<16;j++) pk[j] = stage[mrow][seg+j];
    short8 h0,h1,l0,l1;
    #pragma unroll
    for (int j=0;j<8;j++){
      h0[j]=(short)(pk[j]&0xffff);   l0[j]=(short)(pk[j]>>16);
      h1[j]=(short)(pk[8+j]&0xffff); l1[j]=(short)(pk[8+j]>>16);
    }
    const size_t rb = ((size_t)((bidx*4+hh)*2048 + (m0&2047) + mrow))*64 + seg;
    ushort_t* dh = (sect==0)? qh : kh;
    ushort_t* dl = (sect==0)? ql : kl;
    *(short8*)&dh[rb] = h0; *(short8*)&dh[rb+8] = h1;
    *(short8*)&dl[rb] = l0; *(short8*)&dl[rb+8] = l1;
  } else {
    _Float16 (*trans)[72] = (_Float16(*)[72])stage;
    #pragma unroll
    for (int nt=0;nt<4;nt++){
      #pragma unroll
      for (int r=0;r<4;r++){
        const int m = w*16 + quad*4 + r;
        const int f = nt*16 + lm;
        trans[f][m] = (_Float16)(acc[nt][r] + bias[nloc0 + f]);
      }
    }
    __syncthreads();
    const int d = tid>>2, sc = (tid&3)*16;
    const int bh_ = bidx*4 + hh;
    half8 v0 = *(half8*)&trans[d][sc];
    half8 v1 = *(half8*)&trans[d][sc+8];
    _Float16* dst = vt + ((size_t)bh_*64 + d)*2048 + (m0&2047) + sc;
    *(half8*)dst = v0;
    *(half8*)(dst+8) = v1;
  }
}

// ---------- K3: sparse attention — 3-pass recompute, no spill ----------
__global__ __launch_bounds__(512,4) void attn_kernel(
    const ushort_t* __restrict__ qh, const ushort_t* __restrict__ ql,
    const ushort_t* __restrict__ kh, const ushort_t* __restrict__ kl,
    const _Float16* __restrict__ vt,
    ushort_t* __restrict__ att_h, ushort_t* __restrict__ att_l){
  __shared__ char shbuf[16*TBS*2];          // 16640 B: tbuf u16 / Pb f16 / osum f32
  __shared__ unsigned cand[16][64];
  __shared__ unsigned cnt[16];
  __shared__ unsigned minabL[16];
  __shared__ unsigned p16row[16];
  __shared__ int aboveRow[16];
  __shared__ float thrRow[16], mxfRow[16], zrow[16];
  ushort_t* tbuf = (ushort_t*)shbuf;
  _Float16* Pb   = (_Float16*)shbuf;
  float* osum    = (float*)shbuf;

  const int bh = blockIdx.y;
  const int q0 = blockIdx.x * 16;
  const int tid = threadIdx.x;
  const int w = tid>>6, ln = tid&63;
  const int lm = ln&15, quad = ln>>4, lk = quad*8;
  const int qa = 2*w, qb = 2*w+1;

  const ushort_t* Qh  = qh + ((size_t)bh*2048 + q0)*64;
  const ushort_t* Ql  = ql + ((size_t)bh*2048 + q0)*64;
  const ushort_t* Khb = kh + (size_t)bh*2048*64;
  const ushort_t* Klb = kl + (size_t)bh*2048*64;

  if (tid < 16){ cnt[tid]=0u; minabL[tid]=0xffffffffu; zrow[tid]=0.f; }

  // A-frags (Q rows q0+lm), live across all passes
  const short8 ah0 = ldb8(Qh + lm*64 + lk);
  const short8 ah1 = ldb8(Qh + lm*64 + 32 + lk);
  const short8 al0 = ldb8(Ql + lm*64 + lk);
  const short8 al1 = ldb8(Ql + lm*64 + 32 + lk);

  // ----- pass 1: scores -> u16 tops; wave packs its 2 rows into regs -----
  unsigned sp0[16], sp1[16];
  #pragma unroll
  for (int c=0;c<4;c++){
    floatx4 acc[4];
    score_chunk(Khb, Klb, c*512 + w*64 + lm, lk, ah0,ah1,al0,al1, acc);
    __syncthreads();                       // prev chunk's tbuf reads done (covers init)
    #pragma unroll
    for (int tl=0;tl<4;tl++){
      const int col = w*64 + tl*16 + lm;
      #pragma unroll
      for (int r=0;r<4;r++)
        tbuf[(quad*4+r)*TBS + col] = (ushort_t)(mtu(acc[tl][r]*0.125f) >> 16);
    }
    __syncthreads();
    uint4 pa = *(const uint4*)&tbuf[qa*TBS + ln*8];
    uint4 pb = *(const uint4*)&tbuf[qb*TBS + ln*8];
    sp0[c*4+0]=pa.x; sp0[c*4+1]=pa.y; sp0[c*4+2]=pa.z; sp0[c*4+3]=pa.w;
    sp1[c*4+0]=pb.x; sp1[c*4+1]=pb.y; sp1[c*4+2]=pb.z; sp1[c*4+3]=pb.w;
  }

  // bisect top-16 bits (both rows packed into one wsum)
  unsigned pA=0, pB=0;
  #pragma unroll 1
  for (int bit=15; bit>=0; --bit){
    const unsigned cA = pA | (1u<<bit);
    const unsigned cB = pB | (1u<<bit);
    int n0=0, n1=0;
    #pragma unroll
    for (int i=0;i<16;i++){
      const unsigned r0=sp0[i], r1=sp1[i];
      n0 += ((r0&0xffff)>=cA) + ((r0>>16)>=cA);
      n1 += ((r1&0xffff)>=cB) + ((r1>>16)>=cB);
    }
    int packed = n0 | (n1<<16);
    packed = wsum_i(packed);
    if ((packed & 0xffff) >= 206) pA = cA;
    if ((packed >> 16)    >= 206) pB = cB;
  }
  {
    int a0=0, a1=0;
    unsigned m0u=0, m1u=0;
    #pragma unroll
    for (int i=0;i<16;i++){
      const unsigned r0=sp0[i], r1=sp1[i];
      a0 += ((r0&0xffff)>pA) + ((r0>>16)>pA);
      a1 += ((r1&0xffff)>pB) + ((r1>>16)>pB);
      unsigned h;
      h=r0&0xffff; m0u=h>m0u?h:m0u;  h=r0>>16; m0u=h>m0u?h:m0u;
      h=r1&0xffff; m1u=h>m1u?h:m1u;  h=r1>>16; m1u=h>m1u?h:m1u;
    }
    int packed = a0 | (a1<<16);
    packed = wsum_i(packed);
    #pragma unroll
    for (int m=1;m<64;m<<=1){
      unsigned o=(unsigned)__shfl_xor((int)m0u,m,64); m0u = o>m0u?o:m0u;
      o=(unsigned)__shfl_xor((int)m1u,m,64); m1u = o>m1u?o:m1u;
    }
    if (ln==0){
      p16row[qa]=pA; p16row[qb]=pB;
      aboveRow[qa]=packed & 0xffff; aboveRow[qb]=packed>>16;
      mxfRow[qa]=umt(m0u<<16); mxfRow[qb]=umt(m1u<<16);
    }
  }
  __syncthreads();

  // ----- pass 2 (barrier-free): collect candidates + min-above -----
  {
    unsigned pq[4], mn4[4];
    #pragma unroll
    for (int r=0;r<4;r++){ pq[r]=p16row[quad*4+r]; mn4[r]=0xffffffffu; }
    #pragma unroll 1
    for (int c=0;c<4;c++){
      floatx4 acc[4];
      score_chunk(Khb, Klb, c*512 + w*64 + lm, lk, ah0,ah1,al0,al1, acc);
      #pragma unroll
      for (int tl=0;tl<4;tl++){
        #pragma unroll
        for (int r=0;r<4;r++){
          const unsigned u = mtu(acc[tl][r]*0.125f);
          const unsigned t16 = u>>16;
          if (t16 > pq[r]) mn4[r] = (u < mn4[r]) ? u : mn4[r];
          if (t16 == pq[r]){
            const int q = quad*4+r;
            const unsigned pos = atomicAdd(&cnt[q], 1u);
            if (pos < 64u) cand[q][pos] = u;
          }
        }
      }
    }
    #pragma unroll
    for (int r=0;r<4;r++){
      unsigned z = mn4[r];
      #pragma unroll
      for (int m=1;m<16;m<<=1){
        unsigned o=(unsigned)__shfl_xor((int)z,m,64); z = o<z?o:z;
      }
      if (lm==0) atomicMin(&minabL[quad*4+r], z);
    }
  }
  __syncthreads();

  // ----- exact select per row (wave w: rows 2w, 2w+1) -----
  #pragma unroll 1
  for (int rr=0; rr<2; rr++){
    const int q = 2*w + rr;
    const unsigned ncf = cnt[q];
    if (ncf > 64u){
      if (ln==0) thrRow[q] = umt(p16row[q]<<16);   // astronomically unlikely
      continue;
    }
    const int nc = (int)ncf;
    const int A = aboveRow[q];
    const unsigned v = (ln<nc) ? cand[q][ln] : 0u;
    int rank = 0;
    for (int j=0;j<nc;j++){
      const unsigned cj = cand[q][j];
      rank += (cj > v) || (cj==v && j<ln);
    }
    const int rk = (ln<nc) ? rank : 0x7fff;
    const int j205 = 205 - A;
    unsigned long long b5 = __ballot(rk==j205);
    const unsigned v205u = (unsigned)__shfl((int)v, __ffsll((long long)b5)-1, 64);
    unsigned v204u;
    if (A == 205) v204u = minabL[q];
    else {
      unsigned long long b4 = __ballot(rk==(204-A));
      v204u = (unsigned)__shfl((int)v, __ffsll((long long)b4)-1, 64);
    }
    if (ln==0){
      const double a5 = (double)umt(v205u), a4 = (double)umt(v204u);
      thrRow[q] = (float)(a5 + 0.3*(a4 - a5));
    }
  }
  __syncthreads();

  // ----- pass 3: P (f16, dense-masked) + PV MFMA -----
  float thr4[4], mxf4[4], zp[4];
  #pragma unroll
  for (int r=0;r<4;r++){
    thr4[r]=thrRow[quad*4+r]; mxf4[r]=mxfRow[quad*4+r]; zp[r]=0.f;
  }
  floatx4 opv = {0.f,0.f,0.f,0.f};
  const int nt = w & 3;
  const int kh8 = (w>>2)*8;
  const _Float16* Vtb = vt + (size_t)bh*64*2048 + ((size_t)(nt*16+lm))*2048;

  #pragma unroll 1
  for (int c=0;c<4;c++){
    floatx4 acc[4];
    score_chunk(Khb, Klb, c*512 + w*64 + lm, lk, ah0,ah1,al0,al1, acc);
    __syncthreads();                       // prev chunk's PV reads done
    #pragma unroll
    for (int tl=0;tl<4;tl++){
      const int col = w*64 + tl*16 + lm;
      #pragma unroll
      for (int r=0;r<4;r++){
        const float s = acc[tl][r]*0.125f;
        const float pr = (s >= thr4[r]) ? __expf(s - mxf4[r]) : 0.f;
        zp[r] += pr;
        Pb[(quad*4+r)*TBS + col] = (_Float16)pr;
      }
    }
    __syncthreads();
    #pragma unroll
    for (int kk2=0; kk2<8; kk2++){
      const int kk = kh8 + kk2;
      half8 a = *(half8*)&Pb[lm*TBS + kk*32 + lk];
      half8 b = *(const half8*)&Vtb[c*512 + kk*32 + lk];
      opv = MFMA_F16(a,b,opv);
    }
  }

  #pragma unroll
  for (int r=0;r<4;r++){
    float z = zp[r];
    #pragma unroll
    for (int m=1;m<16;m<<=1) z += __shfl_xor(z,m,64);
    if (lm==0) atomicAdd(&zrow[quad*4+r], z);
  }
  __syncthreads();
  #pragma unroll
  for (int r=0;r<4;r++)
    osum[w*256 + (quad*4 + r)*16 + lm] = opv[r];
  __syncthreads();
  if (w < 4){
    const int b_ = bh>>2, h = bh&3;
    #pragma unroll
    for (int r=0;r<4;r++){
      const int row = quad*4 + r;
      float v = osum[w*256 + row*16 + lm] + osum[(w+4)*256 + row*16 + lm];
      v /= zrow[row];
      const ushort_t hi = f2bf(v);
      const ushort_t lo = f2bf(v - bf2f(hi));
      const size_t oi = ((size_t)(b_*2048 + q0 + row))*256 + h*64 + w*16 + lm;
      att_h[oi] = hi;
      att_l[oi] = lo;
    }
  }
}

// ---------- K4: out = att @ M_b + bo_b, split-bf16 MFMA (3 terms) ----------
__global__ __launch_bounds__(256) void out_mfma(
    const ushort_t* __restrict__ ah_, const ushort_t* __restrict__ al_,
    const ushort_t* __restrict__ mh_, const ushort_t* __restrict__ ml_,
    const float* __restrict__ bo_b, float* __restrict__ out){
  const int bz = blockIdx.z;
  const int m0 = blockIdx.x*64, n0 = blockIdx.y*64;
  const int tid = threadIdx.x, w = tid>>6, ln = tid&63;
  const int lm = ln&15, lko = (ln>>4)*8;
  const size_t arow = (size_t)bz*2048 + m0 + w*16 + lm;

  floatx4 acc[4];
  #pragma unroll
  for (int nt=0;nt<4;nt++){ floatx4 z = {0.f,0.f,0.f,0.f}; acc[nt] = z; }

  for (int k0=0;k0<256;k0+=32){
    short8 a_h = ldb8(&ah_[arow*256 + k0 + lko]);
    short8 a_l = ldb8(&al_[arow*256 + k0 + lko]);
    #pragma unroll
    for (int nt=0;nt<4;nt++){
      const size_t boff = ((size_t)bz*256 + n0 + nt*16 + lm)*256 + k0 + lko;
      short8 b_h = ldb8(&mh_[boff]);
      short8 b_l = ldb8(&ml_[boff]);
      acc[nt] = MFMA_BF(a_h,b_h,acc[nt]);
      acc[nt] = MFMA_BF(a_h,b_l,acc[nt]);
      acc[nt] = MFMA_BF(a_l,b_h,acc[nt]);
    }
  }
  #pragma unroll
  for (int nt=0;nt<4;nt++){
    #pragma unroll
    for (int r=0;r<4;r++){
      const int row = m0 + w*16 + (ln>>4)*4 + r;
      const int col = n0 + nt*16 + lm;
      out[((size_t)bz*2048 + row)*256 + col] = acc[nt][r] + bo_b[bz*256 + col];
    }
  }
}

// ---------- launch ----------
extern "C" void kernel_launch(void* const* d_in, const int* in_sizes, int n_in,
                              void* d_out, int out_size, void* d_ws, size_t ws_size,
                              hipStream_t stream) {
  const float* x   = (const float*)d_in[0];
  const float* Wq  = (const float*)d_in[1];  const float* bq  = (const float*)d_in[2];
  const float* Wk  = (const float*)d_in[3];  const float* bk  = (const float*)d_in[4];
  const float* Wv  = (const float*)d_in[5];  const float* bv  = (const float*)d_in[6];
  const float* Wd  = (const float*)d_in[7];  const float* bd  = (const float*)d_in[8];
  const float* Wg  = (const float*)d_in[9];  const float* bg  = (const float*)d_in[10];
  const float* Wgp = (const float*)d_in[11]; const float* bgp = (const float*)d_in[12];
  const float* Wo  = (const float*)d_in[13]; const float* bo  = (const float*)d_in[14];

  char* base = (char*)d_ws;
  const size_t MB = 1024*1024;
  ushort_t* qh   = (ushort_t*)(base + 0*MB);              // 4 MB each
  ushort_t* ql   = (ushort_t*)(base + 4*MB);
  ushort_t* kh   = (ushort_t*)(base + 8*MB);
  ushort_t* kl   = (ushort_t*)(base + 12*MB);
  _Float16* vt   = (_Float16*)(base + 16*MB);             // 4 MB
  ushort_t* atth = (ushort_t*)(base + 20*MB);             // 4 MB
  ushort_t* attl = (ushort_t*)(base + 24*MB);             // 4 MB
  ushort_t* wh   = (ushort_t*)(base + 28*MB);             // 384 KB
  ushort_t* wl   = (ushort_t*)(base + 28*MB + 512*1024);  // 384 KB
  ushort_t* mt_h = (ushort_t*)(base + 29*MB);             // 512 KB
  ushort_t* mt_l = (ushort_t*)(base + 29*MB + 512*1024);  // 512 KB
  float* bo_b    = (float*)(base + 30*MB);                // 4 KB
  float* xpart   = (float*)(base + 30*MB + 65536);        // 64 KB

  cvt_w_kernel<<<192, 256, 0, stream>>>(Wq, Wk, Wv, wh, wl);
  xpart_kernel<<<dim3(16,4), 256, 0, stream>>>(x, xpart);
  gate_mprep_kernel<<<4, 256, 0, stream>>>(xpart, Wg, bg, Wgp, bgp,
                                           Wd, bd, Wo, bo, mt_h, mt_l, bo_b);
  qkv_mfma<<<dim3(128,12), 256, 0, stream>>>(x, wh, wl, bq, bk, bv,
                                             qh, ql, kh, kl, vt);
  attn_kernel<<<dim3(128,16), 512, 0, stream>>>(qh, ql, kh, kl, vt, atth, attl);
  out_mfma<<<dim3(32,4,4), 256, 0, stream>>>(atth, attl, mt_h, mt_l, bo_b, (float*)d_out);
}

// Round 5
// 588.564 us; speedup vs baseline: 1.1900x; 1.1900x over previous
//
#include <hip/hip_runtime.h>
#include <hip/hip_bf16.h>
#include <math.h>

// B=4, S=2048, D=256, H=4, HD=64; keep top-10% per score row.
// thr = v205 + 0.3*(v204 - v205)  (v_k = (k+1)-th largest)

typedef __attribute__((ext_vector_type(8))) short short8;
typedef __attribute__((ext_vector_type(4))) short short4v;
typedef __attribute__((ext_vector_type(8))) _Float16 half8;
typedef __attribute__((ext_vector_type(4))) float floatx4;
typedef unsigned short ushort_t;

#define MFMA_BF(a,b,c)  __builtin_amdgcn_mfma_f32_16x16x32_bf16(a,b,c,0,0,0)
#define MFMA_F16(a,b,c) __builtin_amdgcn_mfma_f32_16x16x32_f16(a,b,c,0,0,0)

#define TSTRIDE 521   // f32 elems per tbuf row
#define PBS 536       // f16 elems per Pb row (1072 B: 16B-aligned, 2-way-max banks)
#define OSTRIDE 264   // f32 elems per osum row

// ---------- helpers ----------
__device__ __forceinline__ unsigned mtu(float f){
  unsigned u = __float_as_uint(f);
  return (u & 0x80000000u) ? ~u : (u | 0x80000000u);
}
__device__ __forceinline__ float umt(unsigned u){
  return __uint_as_float((u & 0x80000000u) ? (u & 0x7fffffffu) : ~u);
}
__device__ __forceinline__ int wsum_i(int v){
  #pragma unroll
  for (int m=1;m<64;m<<=1) v += __shfl_xor(v,m,64);
  return v;
}
__device__ __forceinline__ float wsum_f(float v){
  #pragma unroll
  for (int m=1;m<64;m<<=1) v += __shfl_xor(v,m,64);
  return v;
}
__device__ __forceinline__ unsigned wmax_u(unsigned v){
  #pragma unroll
  for (int m=1;m<64;m<<=1){ unsigned o=(unsigned)__shfl_xor((int)v,m,64); v = o>v?o:v; }
  return v;
}
__device__ __forceinline__ unsigned wmin_u(unsigned v){
  #pragma unroll
  for (int m=1;m<64;m<<=1){ unsigned o=(unsigned)__shfl_xor((int)v,m,64); v = o<v?o:v; }
  return v;
}
__device__ __forceinline__ ushort_t f2bf(float f){       // RNE f32->bf16
  unsigned u = __float_as_uint(f);
  return (ushort_t)((u + 0x7fffu + ((u>>16)&1u)) >> 16);
}
__device__ __forceinline__ float bf2f(ushort_t u){
  return __uint_as_float(((unsigned)u) << 16);
}
__device__ __forceinline__ short8 ldb8(const ushort_t* p){ return *(const short8*)p; }

// ---------- K0: fp32 -> bf16 hi/lo for W(q|k|v) only ----------
__global__ void cvt_w_kernel(const float* __restrict__ Wq, const float* __restrict__ Wk,
                             const float* __restrict__ Wv,
                             ushort_t* __restrict__ wh, ushort_t* __restrict__ wl){
  const int i = blockIdx.x*256 + threadIdx.x;       // 49152 float4s
  const size_t base = (size_t)i*4;
  const int row = i >> 6;                            // row 0..767
  const float* src = row<256 ? &Wq[base] : (row<512 ? &Wk[base-65536] : &Wv[base-131072]);
  float4 v = *(const float4*)src;
  short4v hv, lv; ushort_t h;
  h=f2bf(v.x); hv.x=(short)h; lv.x=(short)f2bf(v.x-bf2f(h));
  h=f2bf(v.y); hv.y=(short)h; lv.y=(short)f2bf(v.y-bf2f(h));
  h=f2bf(v.z); hv.z=(short)h; lv.z=(short)f2bf(v.z-bf2f(h));
  h=f2bf(v.w); hv.w=(short)h; lv.w=(short)f2bf(v.w-bf2f(h));
  *(short4v*)&wh[base] = hv;
  *(short4v*)&wl[base] = lv;
}

// ---------- K1a: per-(b,chunk) column sums of x ----------
__global__ void xpart_kernel(const float* __restrict__ x, float* __restrict__ xpart){
  const int ch = blockIdx.x, b = blockIdx.y, t = threadIdx.x;
  const float* xp = x + ((size_t)b*2048 + (size_t)ch*128)*256 + t;
  float s = 0.f;
  for (int i=0;i<128;i++) s += xp[(size_t)i*256];
  xpart[(size_t)(b*16+ch)*256 + t] = s;
}

// ---------- K1b: gate + fold distill/gate/out into M_b ----------
__global__ void gate_mprep_kernel(const float* __restrict__ xpart,
    const float* __restrict__ Wg, const float* __restrict__ bg,
    const float* __restrict__ Wgp,const float* __restrict__ bgp,
    const float* __restrict__ Wd, const float* __restrict__ bd,
    const float* __restrict__ Wo, const float* __restrict__ bo,
    ushort_t* __restrict__ mt_h, ushort_t* __restrict__ mt_l,
    float* __restrict__ bo_b){
  __shared__ float xm[256];
  __shared__ float g16[16];
  __shared__ float gs[256];
  __shared__ float coef[256];
  const int b = blockIdx.x, t = threadIdx.x;
  float s = 0.f;
  for (int ch=0; ch<16; ch++) s += xpart[(size_t)(b*16+ch)*256 + t];
  xm[t] = s * (1.0f/2048.0f);
  __syncthreads();
  if (t < 16){
    float z = bg[t];
    for (int d=0; d<256; d++) z = fmaf(xm[d], Wg[t*256+d], z);
    g16[t] = 1.0f/(1.0f + __expf(-z));
  }
  __syncthreads();
  float z2 = bgp[t];
  #pragma unroll
  for (int j=0;j<16;j++) z2 = fmaf(g16[j], Wgp[t*16+j], z2);
  gs[t] = z2;
  coef[t] = z2 * bd[t&15];
  __syncthreads();
  float e[16];
  const int g0 = t & ~15, klo = t & 15;
  #pragma unroll
  for (int m=0;m<16;m++) e[m] = gs[g0+m] * Wd[m*16 + klo];
  const float omg = 1.0f - gs[t];
  for (int j=0;j<256;j++){
    const float* wor = Wo + (size_t)j*256;
    float acc = omg * wor[t];
    #pragma unroll
    for (int m=0;m<16;m++) acc = fmaf(e[m], wor[g0+m], acc);
    const ushort_t hi = f2bf(acc);
    mt_h[((size_t)b*256 + j)*256 + t] = hi;
    mt_l[((size_t)b*256 + j)*256 + t] = f2bf(acc - bf2f(hi));
  }
  float bacc = bo[t];
  const float* worT = Wo + (size_t)t*256;
  for (int i=0;i<256;i++) bacc = fmaf(coef[i], worT[i], bacc);
  bo_b[b*256 + t] = bacc;
}

// ---------- K2: QKV projection, split-bf16 MFMA; x split in-register ----------
__global__ __launch_bounds__(256) void qkv_mfma(
    const float* __restrict__ x,
    const ushort_t* __restrict__ wh, const ushort_t* __restrict__ wl,
    const float* __restrict__ bq, const float* __restrict__ bk, const float* __restrict__ bv,
    ushort_t* __restrict__ qh, ushort_t* __restrict__ ql,
    ushort_t* __restrict__ kh, ushort_t* __restrict__ kl,
    _Float16* __restrict__ vt){
  __shared__ unsigned stage[64][68];
  const int m0 = blockIdx.x*64, n0g = blockIdx.y*64;
  const int sect = n0g >> 8, nloc0 = n0g & 255;
  const int tid = threadIdx.x, w = tid>>6, ln = tid&63;
  const int lm = ln&15, quad = ln>>4, lk = quad*8;
  const int arow = m0 + w*16 + lm;

  floatx4 acc[4];
  #pragma unroll
  for (int nt=0;nt<4;nt++){ floatx4 z = {0.f,0.f,0.f,0.f}; acc[nt] = z; }

  for (int k0=0;k0<256;k0+=32){
    const float* xp = &x[(size_t)arow*256 + k0 + lk];
    float4 xa = *(const float4*)xp;
    float4 xb = *(const float4*)(xp+4);
    float xv[8] = {xa.x,xa.y,xa.z,xa.w,xb.x,xb.y,xb.z,xb.w};
    short8 a_h, a_l;
    #pragma unroll
    for (int j=0;j<8;j++){
      const ushort_t h = f2bf(xv[j]);
      a_h[j] = (short)h;
      a_l[j] = (short)f2bf(xv[j] - bf2f(h));
    }
    #pragma unroll
    for (int nt=0;nt<4;nt++){
      const size_t boff = (size_t)(n0g + nt*16 + lm)*256 + k0 + lk;
      short8 b_h = ldb8(&wh[boff]);
      short8 b_l = ldb8(&wl[boff]);
      acc[nt] = MFMA_BF(a_h,b_h,acc[nt]);
      acc[nt] = MFMA_BF(a_h,b_l,acc[nt]);
      acc[nt] = MFMA_BF(a_l,b_h,acc[nt]);
      acc[nt] = MFMA_BF(a_l,b_l,acc[nt]);
    }
  }

  const float* bias = (sect==0)?bq:((sect==1)?bk:bv);
  const int bidx = m0 >> 11, hh = nloc0 >> 6;
  if (sect < 2){
    #pragma unroll
    for (int nt=0;nt<4;nt++){
      #pragma unroll
      for (int r=0;r<4;r++){
        const int m = w*16 + quad*4 + r;
        const int f = nt*16 + lm;
        const float val = acc[nt][r] + bias[nloc0 + f];
        const ushort_t hi = f2bf(val);
        const ushort_t lo = f2bf(val - bf2f(hi));
        stage[m][f] = (unsigned)hi | ((unsigned)lo << 16);
      }
    }
    __syncthreads();
    const int mrow = tid>>2, seg = (tid&3)*16;
    unsigned pk[16];
    #pragma unroll
    for (int j=0;j<16;j++) pk[j] = stage[mrow][seg+j];
    short8 h0,h1,l0,l1;
    #pragma unroll
    for (int j=0;j<8;j++){
      h0[j]=(short)(pk[j]&0xffff);   l0[j]=(short)(pk[j]>>16);
      h1[j]=(short)(pk[8+j]&0xffff); l1[j]=(short)(pk[8+j]>>16);
    }
    const size_t rb = ((size_t)((bidx*4+hh)*2048 + (m0&2047) + mrow))*64 + seg;
    ushort_t* dh = (sect==0)? qh : kh;
    ushort_t* dl = (sect==0)? ql : kl;
    *(short8*)&dh[rb] = h0; *(short8*)&dh[rb+8] = h1;
    *(short8*)&dl[rb] = l0; *(short8*)&dl[rb+8] = l1;
  } else {
    _Float16 (*trans)[72] = (_Float16(*)[72])stage;
    #pragma unroll
    for (int nt=0;nt<4;nt++){
      #pragma unroll
      for (int r=0;r<4;r++){
        const int m = w*16 + quad*4 + r;
        const int f = nt*16 + lm;
        trans[f][m] = (_Float16)(acc[nt][r] + bias[nloc0 + f]);
      }
    }
    __syncthreads();
    const int d = tid>>2, sc = (tid&3)*16;
    const int bh_ = bidx*4 + hh;
    half8 v0 = *(half8*)&trans[d][sc];
    half8 v1 = *(half8*)&trans[d][sc+8];
    _Float16* dst = vt + ((size_t)bh_*64 + d)*2048 + (m0&2047) + sc;
    *(half8*)dst = v0;
    *(half8*)(dst+8) = v1;
  }
}

// ---------- K3: sparse attention — one wave per score row, score once ----------
__global__ __launch_bounds__(1024,4) void attn_kernel(
    const ushort_t* __restrict__ qh, const ushort_t* __restrict__ ql,
    const ushort_t* __restrict__ kh, const ushort_t* __restrict__ kl,
    const _Float16* __restrict__ vt,
    ushort_t* __restrict__ att_h, ushort_t* __restrict__ att_l){
  __shared__ float shf[8352];        // 33408 B: tbuf f32[16][521] / Pb f16[16][536] / osum f32[16][264]
  __shared__ unsigned cand[16][64];
  __shared__ unsigned cnt[16];
  __shared__ float zsh[16];
  float* tbuf = shf;
  _Float16* Pb = (_Float16*)shf;
  float* osum = shf;

  const int bh = blockIdx.y;
  const int q0 = blockIdx.x * 16;
  const int tid = threadIdx.x;
  const int w = tid>>6, ln = tid&63;          // wave w owns score row w
  const int lm = ln&15, quad = ln>>4, lk = quad*8;

  if (tid < 16) cnt[tid] = 0u;

  const ushort_t* Qh  = qh + ((size_t)bh*2048 + q0)*64;
  const ushort_t* Ql  = ql + ((size_t)bh*2048 + q0)*64;
  const ushort_t* Khb = kh + (size_t)bh*2048*64;
  const ushort_t* Klb = kl + (size_t)bh*2048*64;

  // A-frags: Q rows q0..q0+15 (m = lm)
  const short8 ah0 = ldb8(Qh + lm*64 + lk);
  const short8 ah1 = ldb8(Qh + lm*64 + 32 + lk);
  const short8 al0 = ldb8(Ql + lm*64 + lk);
  const short8 al1 = ldb8(Ql + lm*64 + 32 + lk);

  // ----- phase A: scores (ONCE). wave w computes keys [c*512+w*32, +32) -----
  unsigned su[32];                   // row w's 2048 scores: su[c*8+j] = key c*512+j*64+ln
  #pragma unroll
  for (int c=0;c<4;c++){
    floatx4 acc[2];
    #pragma unroll
    for (int tl=0;tl<2;tl++){
      const size_t ko = (size_t)(c*512 + w*32 + tl*16 + lm)*64 + lk;
      short8 bh0 = ldb8(Khb + ko);
      short8 bh1 = ldb8(Khb + ko + 32);
      short8 bl0 = ldb8(Klb + ko);
      short8 bl1 = ldb8(Klb + ko + 32);
      floatx4 a = {0.f,0.f,0.f,0.f};
      a = MFMA_BF(ah0,bh0,a); a = MFMA_BF(ah1,bh1,a);
      a = MFMA_BF(al0,bh0,a); a = MFMA_BF(al1,bh1,a);
      a = MFMA_BF(ah0,bl0,a); a = MFMA_BF(ah1,bl1,a);
      a = MFMA_BF(al0,bl0,a); a = MFMA_BF(al1,bl1,a);
      acc[tl] = a;
    }
    __syncthreads();                 // prev chunk's tbuf reads done
    #pragma unroll
    for (int tl=0;tl<2;tl++){
      const int col = w*32 + tl*16 + lm;
      #pragma unroll
      for (int r=0;r<4;r++)
        tbuf[(quad*4+r)*TSTRIDE + col] = acc[tl][r]*0.125f;
    }
    __syncthreads();                 // chunk visible
    #pragma unroll
    for (int j=0;j<8;j++)
      su[c*8+j] = mtu(tbuf[w*TSTRIDE + j*64 + ln]);
  }

  // ----- select (wave-local, exact): packed top-16 bisect -----
  unsigned pk[16];
  #pragma unroll
  for (int i=0;i<16;i++)
    pk[i] = (su[2*i]>>16) | (su[2*i+1] & 0xffff0000u);

  unsigned p16 = 0;
  #pragma unroll 1
  for (int bit=15; bit>=0; --bit){
    const unsigned c = p16 | (1u<<bit);
    const unsigned ch_ = c<<16;
    int n = 0;
    #pragma unroll
    for (int i=0;i<16;i++){
      n += ((pk[i]&0xffffu) >= c) ? 1 : 0;
      n += (pk[i] >= ch_) ? 1 : 0;
    }
    n = wsum_i(n);
    if (n >= 206) p16 = c;
  }

  // one scan: above-count, min-above, max, candidate collect (t16==p16)
  int A = 0;
  unsigned mnab = 0xffffffffu, mxu = 0;
  #pragma unroll
  for (int i=0;i<32;i++){
    const unsigned u = su[i];
    mxu = (u > mxu) ? u : mxu;
    const unsigned t16 = u>>16;
    if (t16 > p16){
      A++;
      mnab = (u < mnab) ? u : mnab;
    } else if (t16 == p16){
      const unsigned pos = atomicAdd(&cnt[w], 1u);
      if (pos < 64u) cand[w][pos] = u;
    }
  }
  A = wsum_i(A);
  mnab = wmin_u(mnab);
  mxu = wmax_u(mxu);

  unsigned v205u, v204u;
  const int nc = (int)cnt[w];
  if (nc <= 64){
    const unsigned v = (ln<nc) ? cand[w][ln] : 0u;
    int rank = 0;
    for (int j=0;j<nc;j++){
      const unsigned cj = cand[w][j];
      rank += ((cj > v) || (cj==v && j<ln)) ? 1 : 0;
    }
    const int rk = (ln<nc) ? rank : 0x7fff;
    const int j205 = 205 - A;
    unsigned long long b5 = __ballot(rk==j205);
    v205u = (unsigned)__shfl((int)v, __ffsll((long long)b5)-1, 64);
    if (A == 205) v204u = mnab;
    else {
      unsigned long long b4 = __ballot(rk==(204-A));
      v204u = (unsigned)__shfl((int)v, __ffsll((long long)b4)-1, 64);
    }
  } else {
    // rare: finish bisection over low 16 bits on full values
    unsigned v = p16<<16;
    #pragma unroll 1
    for (int bit=15; bit>=0; --bit){
      const unsigned c = v | (1u<<bit);
      int n = 0;
      #pragma unroll
      for (int i=0;i<32;i++) n += (su[i] >= c) ? 1 : 0;
      n = wsum_i(n);
      if (n >= 206) v = c;
    }
    v205u = v;
    int cgt = 0; unsigned mn = 0xffffffffu;
    #pragma unroll
    for (int i=0;i<32;i++){
      const unsigned u = su[i];
      if (u > v){ cgt++; mn = (u<mn)?u:mn; }
    }
    cgt = wsum_i(cgt);
    mn = wmin_u(mn);
    v204u = (cgt == 205) ? mn : v205u;
  }
  const float a5 = umt(v205u), a4 = umt(v204u);
  const float thr = (float)((double)a5 + 0.3*((double)a4 - (double)a5));
  const float mxf = umt(mxu);

  // ----- phase B: P (f16, dense-masked) + PV MFMA -----
  float zacc = 0.f;
  floatx4 opv = {0.f,0.f,0.f,0.f};
  const int T = w & 3;               // output tile (cols T*16..+16 of head dim)
  const int kseg = w >> 2;           // k-range [kseg*128, +128) within chunk
  const _Float16* Vtb = vt + (size_t)bh*64*2048 + ((size_t)(T*16+lm))*2048;

  #pragma unroll
  for (int c=0;c<4;c++){
    __syncthreads();                 // prev chunk's PV reads done / tbuf free
    #pragma unroll
    for (int j=0;j<8;j++){
      const float s = umt(su[c*8+j]);
      const float pr = (s >= thr) ? __expf(s - mxf) : 0.f;
      zacc += pr;
      Pb[w*PBS + j*64 + ln] = (_Float16)pr;
    }
    __syncthreads();                 // P visible
    #pragma unroll
    for (int kk=0; kk<4; kk++){
      const int ko = kseg*128 + kk*32 + lk;
      half8 a = *(half8*)&Pb[lm*PBS + ko];
      half8 b = *(const half8*)&Vtb[c*512 + ko];
      opv = MFMA_F16(a,b,opv);
    }
  }

  const float Z = wsum_f(zacc);
  if (ln == 0) zsh[w] = Z;
  __syncthreads();                   // last PV reads done; Pb -> osum reuse
  #pragma unroll
  for (int r=0;r<4;r++)
    osum[w*OSTRIDE + (quad*4+r)*16 + lm] = opv[r];
  __syncthreads();
  {
    const int b_ = bh>>2, h = bh&3;
    const int Tt = tid>>8, idx = tid&255;
    const int row = idx>>4, cl = idx&15;
    float v = osum[(0*4+Tt)*OSTRIDE + idx] + osum[(1*4+Tt)*OSTRIDE + idx]
            + osum[(2*4+Tt)*OSTRIDE + idx] + osum[(3*4+Tt)*OSTRIDE + idx];
    v /= zsh[row];
    const ushort_t hi = f2bf(v);
    const ushort_t lo = f2bf(v - bf2f(hi));
    const size_t oi = ((size_t)(b_*2048 + q0 + row))*256 + h*64 + Tt*16 + cl;
    att_h[oi] = hi;
    att_l[oi] = lo;
  }
}

// ---------- K4: out = att @ M_b + bo_b, split-bf16 MFMA (3 terms) ----------
__global__ __launch_bounds__(256) void out_mfma(
    const ushort_t* __restrict__ ah_, const ushort_t* __restrict__ al_,
    const ushort_t* __restrict__ mh_, const ushort_t* __restrict__ ml_,
    const float* __restrict__ bo_b, float* __restrict__ out){
  const int bz = blockIdx.z;
  const int m0 = blockIdx.x*64, n0 = blockIdx.y*64;
  const int tid = threadIdx.x, w = tid>>6, ln = tid&63;
  const int lm = ln&15, lko = (ln>>4)*8;
  const size_t arow = (size_t)bz*2048 + m0 + w*16 + lm;

  floatx4 acc[4];
  #pragma unroll
  for (int nt=0;nt<4;nt++){ floatx4 z = {0.f,0.f,0.f,0.f}; acc[nt] = z; }

  for (int k0=0;k0<256;k0+=32){
    short8 a_h = ldb8(&ah_[arow*256 + k0 + lko]);
    short8 a_l = ldb8(&al_[arow*256 + k0 + lko]);
    #pragma unroll
    for (int nt=0;nt<4;nt++){
      const size_t boff = ((size_t)bz*256 + n0 + nt*16 + lm)*256 + k0 + lko;
      short8 b_h = ldb8(&mh_[boff]);
      short8 b_l = ldb8(&ml_[boff]);
      acc[nt] = MFMA_BF(a_h,b_h,acc[nt]);
      acc[nt] = MFMA_BF(a_h,b_l,acc[nt]);
      acc[nt] = MFMA_BF(a_l,b_h,acc[nt]);
    }
  }
  #pragma unroll
  for (int nt=0;nt<4;nt++){
    #pragma unroll
    for (int r=0;r<4;r++){
      const int row = m0 + w*16 + (ln>>4)*4 + r;
      const int col = n0 + nt*16 + lm;
      out[((size_t)bz*2048 + row)*256 + col] = acc[nt][r] + bo_b[bz*256 + col];
    }
  }
}

// ---------- launch ----------
extern "C" void kernel_launch(void* const* d_in, const int* in_sizes, int n_in,
                              void* d_out, int out_size, void* d_ws, size_t ws_size,
                              hipStream_t stream) {
  const float* x   = (const float*)d_in[0];
  const float* Wq  = (const float*)d_in[1];  const float* bq  = (const float*)d_in[2];
  const float* Wk  = (const float*)d_in[3];  const float* bk  = (const float*)d_in[4];
  const float* Wv  = (const float*)d_in[5];  const float* bv  = (const float*)d_in[6];
  const float* Wd  = (const float*)d_in[7];  const float* bd  = (const float*)d_in[8];
  const float* Wg  = (const float*)d_in[9];  const float* bg  = (const float*)d_in[10];
  const float* Wgp = (const float*)d_in[11]; const float* bgp = (const float*)d_in[12];
  const float* Wo  = (const float*)d_in[13]; const float* bo  = (const float*)d_in[14];

  char* base = (char*)d_ws;
  const size_t MB = 1024*1024;
  ushort_t* qh   = (ushort_t*)(base + 0*MB);
  ushort_t* ql   = (ushort_t*)(base + 4*MB);
  ushort_t* kh   = (ushort_t*)(base + 8*MB);
  ushort_t* kl   = (ushort_t*)(base + 12*MB);
  _Float16* vt   = (_Float16*)(base + 16*MB);
  ushort_t* atth = (ushort_t*)(base + 20*MB);
  ushort_t* attl = (ushort_t*)(base + 24*MB);
  ushort_t* wh   = (ushort_t*)(base + 28*MB);
  ushort_t* wl   = (ushort_t*)(base + 28*MB + 512*1024);
  ushort_t* mt_h = (ushort_t*)(base + 29*MB);
  ushort_t* mt_l = (ushort_t*)(base + 29*MB + 512*1024);
  float* bo_b    = (float*)(base + 30*MB);
  float* xpart   = (float*)(base + 30*MB + 65536);

  cvt_w_kernel<<<192, 256, 0, stream>>>(Wq, Wk, Wv, wh, wl);
  xpart_kernel<<<dim3(16,4), 256, 0, stream>>>(x, xpart);
  gate_mprep_kernel<<<4, 256, 0, stream>>>(xpart, Wg, bg, Wgp, bgp,
                                           Wd, bd, Wo, bo, mt_h, mt_l, bo_b);
  qkv_mfma<<<dim3(128,12), 256, 0, stream>>>(x, wh, wl, bq, bk, bv,
                                             qh, ql, kh, kl, vt);
  attn_kernel<<<dim3(128,16), 1024, 0, stream>>>(qh, ql, kh, kl, vt, atth, attl);
  out_mfma<<<dim3(32,4,4), 256, 0, stream>>>(atth, attl, mt_h, mt_l, bo_b, (float*)d_out);
}

// Round 6
// 568.058 us; speedup vs baseline: 1.2330x; 1.0361x over previous
//
#include <hip/hip_runtime.h>
#include <hip/hip_bf16.h>
#include <math.h>

// B=4, S=2048, D=256, H=4, HD=64; keep top-10% per score row.
// thr = v205 + 0.3*(v204 - v205)  (v_k = (k+1)-th largest)

typedef __attribute__((ext_vector_type(8))) short short8;
typedef __attribute__((ext_vector_type(4))) short short4v;
typedef __attribute__((ext_vector_type(8))) _Float16 half8;
typedef __attribute__((ext_vector_type(4))) _Float16 half4;
typedef __attribute__((ext_vector_type(4))) float floatx4;
typedef unsigned short ushort_t;

#define MFMA_BF(a,b,c)  __builtin_amdgcn_mfma_f32_16x16x32_bf16(a,b,c,0,0,0)
#define MFMA_F16(a,b,c) __builtin_amdgcn_mfma_f32_16x16x32_f16(a,b,c,0,0,0)

#define TS  532   // f32 elems per tbuf row: 16B-aligned rows, 2-way-free writes
#define PBS 536   // f16 elems per Pb row (16B-aligned rows)
#define OSTRIDE 264

// ---------- helpers ----------
__device__ __forceinline__ unsigned mtu(float f){
  unsigned u = __float_as_uint(f);
  return (u & 0x80000000u) ? ~u : (u | 0x80000000u);
}
__device__ __forceinline__ float umt(unsigned u){
  return __uint_as_float((u & 0x80000000u) ? (u & 0x7fffffffu) : ~u);
}
__device__ __forceinline__ int wsum_i(int v){
  #pragma unroll
  for (int m=1;m<64;m<<=1) v += __shfl_xor(v,m,64);
  return v;
}
__device__ __forceinline__ float wsum_f(float v){
  #pragma unroll
  for (int m=1;m<64;m<<=1) v += __shfl_xor(v,m,64);
  return v;
}
__device__ __forceinline__ unsigned wmax_u(unsigned v){
  #pragma unroll
  for (int m=1;m<64;m<<=1){ unsigned o=(unsigned)__shfl_xor((int)v,m,64); v = o>v?o:v; }
  return v;
}
__device__ __forceinline__ unsigned wmin_u(unsigned v){
  #pragma unroll
  for (int m=1;m<64;m<<=1){ unsigned o=(unsigned)__shfl_xor((int)v,m,64); v = o<v?o:v; }
  return v;
}
__device__ __forceinline__ ushort_t f2bf(float f){       // RNE f32->bf16
  unsigned u = __float_as_uint(f);
  return (ushort_t)((u + 0x7fffu + ((u>>16)&1u)) >> 16);
}
__device__ __forceinline__ float bf2f(ushort_t u){
  return __uint_as_float(((unsigned)u) << 16);
}
__device__ __forceinline__ short8 ldb8(const ushort_t* p){ return *(const short8*)p; }

// ---------- K0: fused W-cvt (192 blocks) + xpart (64 blocks) ----------
__global__ void cvtx_kernel(const float* __restrict__ Wq, const float* __restrict__ Wk,
                            const float* __restrict__ Wv, const float* __restrict__ x,
                            ushort_t* __restrict__ wh, ushort_t* __restrict__ wl,
                            float* __restrict__ xpart){
  const int bid = blockIdx.x, tid = threadIdx.x;
  if (bid < 192){
    const int i = bid*256 + tid;
    const size_t base = (size_t)i*4;
    const int row = i >> 6;
    const float* src = row<256 ? &Wq[base] : (row<512 ? &Wk[base-65536] : &Wv[base-131072]);
    float4 v = *(const float4*)src;
    short4v hv, lv; ushort_t h;
    h=f2bf(v.x); hv.x=(short)h; lv.x=(short)f2bf(v.x-bf2f(h));
    h=f2bf(v.y); hv.y=(short)h; lv.y=(short)f2bf(v.y-bf2f(h));
    h=f2bf(v.z); hv.z=(short)h; lv.z=(short)f2bf(v.z-bf2f(h));
    h=f2bf(v.w); hv.w=(short)h; lv.w=(short)f2bf(v.w-bf2f(h));
    *(short4v*)&wh[base] = hv;
    *(short4v*)&wl[base] = lv;
  } else {
    const int id = bid - 192;
    const int ch = id & 15, b = id >> 4;
    const float* xp = x + ((size_t)b*2048 + (size_t)ch*128)*256 + tid;
    float s = 0.f;
    for (int i=0;i<128;i++) s += xp[(size_t)i*256];
    xpart[(size_t)(b*16+ch)*256 + tid] = s;
  }
}

// ---------- K1: gate + fold distill/gate/out into M_b (64 blocks) ----------
__global__ void gate_mprep_kernel(const float* __restrict__ xpart,
    const float* __restrict__ Wg, const float* __restrict__ bg,
    const float* __restrict__ Wgp,const float* __restrict__ bgp,
    const float* __restrict__ Wd, const float* __restrict__ bd,
    const float* __restrict__ Wo, const float* __restrict__ bo,
    ushort_t* __restrict__ mt_h, ushort_t* __restrict__ mt_l,
    float* __restrict__ bo_b){
  __shared__ float xm[256];
  __shared__ float g16[16];
  __shared__ float gs[256];
  __shared__ float coef[256];
  const int jc = blockIdx.x, b = blockIdx.y, t = threadIdx.x;
  float s = 0.f;
  for (int ch=0; ch<16; ch++) s += xpart[(size_t)(b*16+ch)*256 + t];
  xm[t] = s * (1.0f/2048.0f);
  __syncthreads();
  if (t < 16){
    float z = bg[t];
    for (int d=0; d<256; d++) z = fmaf(xm[d], Wg[t*256+d], z);
    g16[t] = 1.0f/(1.0f + __expf(-z));
  }
  __syncthreads();
  float z2 = bgp[t];
  #pragma unroll
  for (int j=0;j<16;j++) z2 = fmaf(g16[j], Wgp[t*16+j], z2);
  gs[t] = z2;
  coef[t] = z2 * bd[t&15];
  __syncthreads();
  // M columns: thread t = column k; this block does rows j = jc*16 .. +16
  float e[16];
  const int g0 = t & ~15, klo = t & 15;
  #pragma unroll
  for (int m=0;m<16;m++) e[m] = gs[g0+m] * Wd[m*16 + klo];
  const float omg = 1.0f - gs[t];
  #pragma unroll 1
  for (int jj=0;jj<16;jj++){
    const int j = jc*16 + jj;
    const float* wor = Wo + (size_t)j*256;
    float acc = omg * wor[t];
    #pragma unroll
    for (int m=0;m<16;m++) acc = fmaf(e[m], wor[g0+m], acc);
    const ushort_t hi = f2bf(acc);
    mt_h[((size_t)b*256 + j)*256 + t] = hi;
    mt_l[((size_t)b*256 + j)*256 + t] = f2bf(acc - bf2f(hi));
  }
  if (jc == 0){
    float bacc = bo[t];
    const float* worT = Wo + (size_t)t*256;
    for (int i=0;i<256;i++) bacc = fmaf(coef[i], worT[i], bacc);
    bo_b[b*256 + t] = bacc;
  }
}

// ---------- K2: QKV projection, split-bf16 MFMA, LDS-staged tiles ----------
__global__ __launch_bounds__(256) void qkv_mfma(
    const float* __restrict__ x,
    const ushort_t* __restrict__ wh, const ushort_t* __restrict__ wl,
    const float* __restrict__ bq, const float* __restrict__ bk, const float* __restrict__ bv,
    ushort_t* __restrict__ qh, ushort_t* __restrict__ ql,
    ushort_t* __restrict__ kh, ushort_t* __restrict__ kl,
    _Float16* __restrict__ vt){
  __shared__ char shraw[19456];
  float    (*xs)[36]  = (float(*)[36])shraw;                  // 9216 B
  ushort_t (*wsh)[40] = (ushort_t(*)[40])(shraw + 9216);      // 5120 B
  ushort_t (*wsl)[40] = (ushort_t(*)[40])(shraw + 14336);     // 5120 B
  unsigned (*stage)[68] = (unsigned(*)[68])shraw;             // 17408 B (epilogue)

  const int m0 = blockIdx.x*64, n0g = blockIdx.y*64;
  const int sect = n0g >> 8, nloc0 = n0g & 255;
  const int tid = threadIdx.x, w = tid>>6, ln = tid&63;
  const int lm = ln&15, quad = ln>>4, lk = quad*8;

  floatx4 acc[4];
  #pragma unroll
  for (int nt=0;nt<4;nt++){ floatx4 z = {0.f,0.f,0.f,0.f}; acc[nt] = z; }

  const int sr = tid>>3, sc4 = (tid&7)*4;     // x staging coords
  const int wr = tid>>2, wc8 = (tid&3)*8;     // W staging coords

  #pragma unroll 1
  for (int k0=0;k0<256;k0+=32){
    __syncthreads();
    {
      float4 v0 = *(const float4*)&x[(size_t)(m0+sr)*256 + k0 + sc4];
      float4 v1 = *(const float4*)&x[(size_t)(m0+32+sr)*256 + k0 + sc4];
      *(float4*)&xs[sr][sc4] = v0;
      *(float4*)&xs[32+sr][sc4] = v1;
      const size_t off = (size_t)(n0g + wr)*256 + k0 + wc8;
      *(short8*)&wsh[wr][wc8] = ldb8(&wh[off]);
      *(short8*)&wsl[wr][wc8] = ldb8(&wl[off]);
    }
    __syncthreads();
    float4 xa = *(const float4*)&xs[w*16+lm][lk];
    float4 xb = *(const float4*)&xs[w*16+lm][lk+4];
    float xv[8] = {xa.x,xa.y,xa.z,xa.w,xb.x,xb.y,xb.z,xb.w};
    short8 a_h, a_l;
    #pragma unroll
    for (int j=0;j<8;j++){
      const ushort_t h = f2bf(xv[j]);
      a_h[j] = (short)h;
      a_l[j] = (short)f2bf(xv[j] - bf2f(h));
    }
    #pragma unroll
    for (int nt=0;nt<4;nt++){
      short8 b_h = *(const short8*)&wsh[nt*16+lm][lk];
      short8 b_l = *(const short8*)&wsl[nt*16+lm][lk];
      acc[nt] = MFMA_BF(a_h,b_h,acc[nt]);
      acc[nt] = MFMA_BF(a_h,b_l,acc[nt]);
      acc[nt] = MFMA_BF(a_l,b_h,acc[nt]);
      acc[nt] = MFMA_BF(a_l,b_l,acc[nt]);
    }
  }
  __syncthreads();                            // k-loop LDS reads done; reuse as stage

  const float* bias = (sect==0)?bq:((sect==1)?bk:bv);
  const int bidx = m0 >> 11, hh = nloc0 >> 6;
  if (sect < 2){
    #pragma unroll
    for (int nt=0;nt<4;nt++){
      #pragma unroll
      for (int r=0;r<4;r++){
        const int m = w*16 + quad*4 + r;
        const int f = nt*16 + lm;
        const float val = acc[nt][r] + bias[nloc0 + f];
        const ushort_t hi = f2bf(val);
        const ushort_t lo = f2bf(val - bf2f(hi));
        stage[m][f] = (unsigned)hi | ((unsigned)lo << 16);
      }
    }
    __syncthreads();
    const int mrow = tid>>2, seg = (tid&3)*16;
    unsigned pk[16];
    #pragma unroll
    for (int j=0;j<16;j++) pk[j] = stage[mrow][seg+j];
    short8 h0,h1,l0,l1;
    #pragma unroll
    for (int j=0;j<8;j++){
      h0[j]=(short)(pk[j]&0xffff);   l0[j]=(short)(pk[j]>>16);
      h1[j]=(short)(pk[8+j]&0xffff); l1[j]=(short)(pk[8+j]>>16);
    }
    const size_t rb = ((size_t)((bidx*4+hh)*2048 + (m0&2047) + mrow))*64 + seg;
    ushort_t* dh = (sect==0)? qh : kh;
    ushort_t* dl = (sect==0)? ql : kl;
    *(short8*)&dh[rb] = h0; *(short8*)&dh[rb+8] = h1;
    *(short8*)&dl[rb] = l0; *(short8*)&dl[rb+8] = l1;
  } else {
    _Float16 (*trans)[72] = (_Float16(*)[72])shraw;
    #pragma unroll
    for (int nt=0;nt<4;nt++){
      #pragma unroll
      for (int r=0;r<4;r++){
        const int m = w*16 + quad*4 + r;
        const int f = nt*16 + lm;
        trans[f][m] = (_Float16)(acc[nt][r] + bias[nloc0 + f]);
      }
    }
    __syncthreads();
    const int d = tid>>2, sc = (tid&3)*16;
    const int bh_ = bidx*4 + hh;
    half8 v0 = *(half8*)&trans[d][sc];
    half8 v1 = *(half8*)&trans[d][sc+8];
    _Float16* dst = vt + ((size_t)bh_*64 + d)*2048 + (m0&2047) + sc;
    *(half8*)dst = v0;
    *(half8*)(dst+8) = v1;
  }
}

// ---------- K3: sparse attention — one wave per score row, 2 blocks/CU ----------
__global__ __launch_bounds__(1024,8) void attn_kernel(
    const ushort_t* __restrict__ qh, const ushort_t* __restrict__ ql,
    const ushort_t* __restrict__ kh, const ushort_t* __restrict__ kl,
    const _Float16* __restrict__ vt,
    ushort_t* __restrict__ att_h, ushort_t* __restrict__ att_l){
  __shared__ float shf[16*TS];       // 34048 B: tbuf f32 / Pb f16 / osum f32
  __shared__ unsigned cand[16][64];
  __shared__ unsigned cnt[16];
  __shared__ float zsh[16];
  float* tbuf = shf;
  _Float16* Pb = (_Float16*)shf;
  float* osum = shf;

  const int bh = blockIdx.y;
  const int q0 = blockIdx.x * 16;
  const int tid = threadIdx.x;
  const int w = tid>>6, ln = tid&63;          // wave w owns score row w
  const int lm = ln&15, quad = ln>>4, lk = quad*8;

  if (tid < 16) cnt[tid] = 0u;

  const ushort_t* Qh  = qh + ((size_t)bh*2048 + q0)*64;
  const ushort_t* Ql  = ql + ((size_t)bh*2048 + q0)*64;
  const ushort_t* Khb = kh + (size_t)bh*2048*64;
  const ushort_t* Klb = kl + (size_t)bh*2048*64;

  const short8 ah0 = ldb8(Qh + lm*64 + lk);
  const short8 ah1 = ldb8(Qh + lm*64 + 32 + lk);
  const short8 al0 = ldb8(Ql + lm*64 + lk);
  const short8 al1 = ldb8(Ql + lm*64 + 32 + lk);

  // ----- phase A: scores (once); su[c*8+j]: j<4 -> key c*512+4ln+j, else c*512+256+4ln+(j-4)
  unsigned su[32];
  #pragma unroll
  for (int c=0;c<4;c++){
    floatx4 acc[2];
    #pragma unroll
    for (int tl=0;tl<2;tl++){
      const size_t ko = (size_t)(c*512 + w*32 + tl*16 + lm)*64 + lk;
      short8 bh0 = ldb8(Khb + ko);
      short8 bh1 = ldb8(Khb + ko + 32);
      short8 bl0 = ldb8(Klb + ko);
      short8 bl1 = ldb8(Klb + ko + 32);
      floatx4 a = {0.f,0.f,0.f,0.f};
      a = MFMA_BF(ah0,bh0,a); a = MFMA_BF(ah1,bh1,a);
      a = MFMA_BF(al0,bh0,a); a = MFMA_BF(al1,bh1,a);
      a = MFMA_BF(ah0,bl0,a); a = MFMA_BF(ah1,bl1,a);
      a = MFMA_BF(al0,bl0,a); a = MFMA_BF(al1,bl1,a);
      acc[tl] = a;
    }
    __syncthreads();                 // prev chunk's tbuf reads done
    #pragma unroll
    for (int tl=0;tl<2;tl++){
      const int col = w*32 + tl*16 + lm;
      #pragma unroll
      for (int r=0;r<4;r++)
        tbuf[(quad*4+r)*TS + col] = acc[tl][r]*0.125f;
    }
    __syncthreads();                 // chunk visible
    float4 ra0 = *(const float4*)&tbuf[w*TS + 4*ln];
    float4 ra1 = *(const float4*)&tbuf[w*TS + 256 + 4*ln];
    const int o = c*8;
    su[o+0]=mtu(ra0.x); su[o+1]=mtu(ra0.y); su[o+2]=mtu(ra0.z); su[o+3]=mtu(ra0.w);
    su[o+4]=mtu(ra1.x); su[o+5]=mtu(ra1.y); su[o+6]=mtu(ra1.z); su[o+7]=mtu(ra1.w);
  }

  // ----- select (wave-local, exact): packed top-16 bisect -----
  unsigned pk[16];
  #pragma unroll
  for (int i=0;i<16;i++)
    pk[i] = (su[2*i]>>16) | (su[2*i+1] & 0xffff0000u);

  unsigned p16 = 0;
  #pragma unroll 1
  for (int bit=15; bit>=0; --bit){
    const unsigned c = p16 | (1u<<bit);
    const unsigned ch_ = c<<16;
    int n = 0;
    #pragma unroll
    for (int i=0;i<16;i++){
      n += ((pk[i]&0xffffu) >= c) ? 1 : 0;
      n += (pk[i] >= ch_) ? 1 : 0;
    }
    n = wsum_i(n);
    if (n >= 206) p16 = c;
  }

  int A = 0;
  unsigned mnab = 0xffffffffu, mxu = 0;
  #pragma unroll
  for (int i=0;i<32;i++){
    const unsigned u = su[i];
    mxu = (u > mxu) ? u : mxu;
    const unsigned t16 = u>>16;
    if (t16 > p16){
      A++;
      mnab = (u < mnab) ? u : mnab;
    } else if (t16 == p16){
      const unsigned pos = atomicAdd(&cnt[w], 1u);
      if (pos < 64u) cand[w][pos] = u;
    }
  }
  A = wsum_i(A);
  mnab = wmin_u(mnab);
  mxu = wmax_u(mxu);

  unsigned v205u, v204u;
  const int nc = (int)cnt[w];
  if (nc <= 64){
    const unsigned v = (ln<nc) ? cand[w][ln] : 0u;
    int rank = 0;
    for (int j=0;j<nc;j++){
      const unsigned cj = cand[w][j];
      rank += ((cj > v) || (cj==v && j<ln)) ? 1 : 0;
    }
    const int rk = (ln<nc) ? rank : 0x7fff;
    const int j205 = 205 - A;
    unsigned long long b5 = __ballot(rk==j205);
    v205u = (unsigned)__shfl((int)v, __ffsll((long long)b5)-1, 64);
    if (A == 205) v204u = mnab;
    else {
      unsigned long long b4 = __ballot(rk==(204-A));
      v204u = (unsigned)__shfl((int)v, __ffsll((long long)b4)-1, 64);
    }
  } else {
    unsigned v = p16<<16;
    #pragma unroll 1
    for (int bit=15; bit>=0; --bit){
      const unsigned c = v | (1u<<bit);
      int n = 0;
      #pragma unroll
      for (int i=0;i<32;i++) n += (su[i] >= c) ? 1 : 0;
      n = wsum_i(n);
      if (n >= 206) v = c;
    }
    v205u = v;
    int cgt = 0; unsigned mn = 0xffffffffu;
    #pragma unroll
    for (int i=0;i<32;i++){
      const unsigned u = su[i];
      if (u > v){ cgt++; mn = (u<mn)?u:mn; }
    }
    cgt = wsum_i(cgt);
    mn = wmin_u(mn);
    v204u = (cgt == 205) ? mn : v205u;
  }
  const float a5 = umt(v205u), a4 = umt(v204u);
  const float thr = (float)((double)a5 + 0.3*((double)a4 - (double)a5));
  const float mxf = umt(mxu);

  // ----- phase B: P (f16, dense-masked, vectorized) + PV MFMA -----
  float zacc = 0.f;
  floatx4 opv = {0.f,0.f,0.f,0.f};
  const int T = w & 3;
  const int kseg = w >> 2;
  const _Float16* Vtb = vt + (size_t)bh*64*2048 + ((size_t)(T*16+lm))*2048;

  #pragma unroll
  for (int c=0;c<4;c++){
    __syncthreads();                 // prev chunk's PV reads done / tbuf free
    half4 s0, s1;
    #pragma unroll
    for (int j=0;j<8;j++){
      const float s = umt(su[c*8+j]);
      const float pr = (s >= thr) ? __expf(s - mxf) : 0.f;
      zacc += pr;
      if (j<4) s0[j] = (_Float16)pr; else s1[j-4] = (_Float16)pr;
    }
    *(half4*)&Pb[w*PBS + 4*ln]       = s0;
    *(half4*)&Pb[w*PBS + 256 + 4*ln] = s1;
    __syncthreads();                 // P visible
    #pragma unroll
    for (int kk=0; kk<4; kk++){
      const int ko = kseg*128 + kk*32 + lk;
      half8 a = *(half8*)&Pb[lm*PBS + ko];
      half8 b = *(const half8*)&Vtb[c*512 + ko];
      opv = MFMA_F16(a,b,opv);
    }
  }

  const float Z = wsum_f(zacc);
  if (ln == 0) zsh[w] = Z;
  __syncthreads();
  #pragma unroll
  for (int r=0;r<4;r++)
    osum[w*OSTRIDE + (quad*4+r)*16 + lm] = opv[r];
  __syncthreads();
  {
    const int b_ = bh>>2, h = bh&3;
    const int Tt = tid>>8, idx = tid&255;
    const int row = idx>>4, cl = idx&15;
    float v = osum[(0*4+Tt)*OSTRIDE + idx] + osum[(1*4+Tt)*OSTRIDE + idx]
            + osum[(2*4+Tt)*OSTRIDE + idx] + osum[(3*4+Tt)*OSTRIDE + idx];
    v /= zsh[row];
    const ushort_t hi = f2bf(v);
    const ushort_t lo = f2bf(v - bf2f(hi));
    const size_t oi = ((size_t)(b_*2048 + q0 + row))*256 + h*64 + Tt*16 + cl;
    att_h[oi] = hi;
    att_l[oi] = lo;
  }
}

// ---------- K4: out = att @ M_b + bo_b, split-bf16 MFMA, LDS-staged ----------
__global__ __launch_bounds__(256) void out_mfma(
    const ushort_t* __restrict__ ah_, const ushort_t* __restrict__ al_,
    const ushort_t* __restrict__ mh_, const ushort_t* __restrict__ ml_,
    const float* __restrict__ bo_b, float* __restrict__ out){
  __shared__ ushort_t ash[64][40], asl[64][40], msh[64][40], msl[64][40];  // 20480 B
  const int bz = blockIdx.z;
  const int m0 = blockIdx.x*64, n0 = blockIdx.y*64;
  const int tid = threadIdx.x, w = tid>>6, ln = tid&63;
  const int lm = ln&15, lk = (ln>>4)*8;
  const size_t abase = (size_t)bz*2048 + m0;
  const size_t mbase = (size_t)bz*256 + n0;
  const int wr = tid>>2, wc8 = (tid&3)*8;

  floatx4 acc[4];
  #pragma unroll
  for (int nt=0;nt<4;nt++){ floatx4 z = {0.f,0.f,0.f,0.f}; acc[nt] = z; }

  #pragma unroll 1
  for (int k0=0;k0<256;k0+=32){
    __syncthreads();
    {
      const size_t aoff = (abase + wr)*256 + k0 + wc8;
      const size_t moff = (mbase + wr)*256 + k0 + wc8;
      *(short8*)&ash[wr][wc8] = ldb8(&ah_[aoff]);
      *(short8*)&asl[wr][wc8] = ldb8(&al_[aoff]);
      *(short8*)&msh[wr][wc8] = ldb8(&mh_[moff]);
      *(short8*)&msl[wr][wc8] = ldb8(&ml_[moff]);
    }
    __syncthreads();
    short8 a_h = *(const short8*)&ash[w*16+lm][lk];
    short8 a_l = *(const short8*)&asl[w*16+lm][lk];
    #pragma unroll
    for (int nt=0;nt<4;nt++){
      short8 b_h = *(const short8*)&msh[nt*16+lm][lk];
      short8 b_l = *(const short8*)&msl[nt*16+lm][lk];
      acc[nt] = MFMA_BF(a_h,b_h,acc[nt]);
      acc[nt] = MFMA_BF(a_h,b_l,acc[nt]);
      acc[nt] = MFMA_BF(a_l,b_h,acc[nt]);
    }
  }
  #pragma unroll
  for (int nt=0;nt<4;nt++){
    #pragma unroll
    for (int r=0;r<4;r++){
      const int row = m0 + w*16 + (ln>>4)*4 + r;
      const int col = n0 + nt*16 + lm;
      out[((size_t)bz*2048 + row)*256 + col] = acc[nt][r] + bo_b[bz*256 + col];
    }
  }
}

// ---------- launch ----------
extern "C" void kernel_launch(void* const* d_in, const int* in_sizes, int n_in,
                              void* d_out, int out_size, void* d_ws, size_t ws_size,
                              hipStream_t stream) {
  const float* x   = (const float*)d_in[0];
  const float* Wq  = (const float*)d_in[1];  const float* bq  = (const float*)d_in[2];
  const float* Wk  = (const float*)d_in[3];  const float* bk  = (const float*)d_in[4];
  const float* Wv  = (const float*)d_in[5];  const float* bv  = (const float*)d_in[6];
  const float* Wd  = (const float*)d_in[7];  const float* bd  = (const float*)d_in[8];
  const float* Wg  = (const float*)d_in[9];  const float* bg  = (const float*)d_in[10];
  const float* Wgp = (const float*)d_in[11]; const float* bgp = (const float*)d_in[12];
  const float* Wo  = (const float*)d_in[13]; const float* bo  = (const float*)d_in[14];

  char* base = (char*)d_ws;
  const size_t MB = 1024*1024;
  ushort_t* qh   = (ushort_t*)(base + 0*MB);
  ushort_t* ql   = (ushort_t*)(base + 4*MB);
  ushort_t* kh   = (ushort_t*)(base + 8*MB);
  ushort_t* kl   = (ushort_t*)(base + 12*MB);
  _Float16* vt   = (_Float16*)(base + 16*MB);
  ushort_t* atth = (ushort_t*)(base + 20*MB);
  ushort_t* attl = (ushort_t*)(base + 24*MB);
  ushort_t* wh   = (ushort_t*)(base + 28*MB);
  ushort_t* wl   = (ushort_t*)(base + 28*MB + 512*1024);
  ushort_t* mt_h = (ushort_t*)(base + 29*MB);
  ushort_t* mt_l = (ushort_t*)(base + 29*MB + 512*1024);
  float* bo_b    = (float*)(base + 30*MB);
  float* xpart   = (float*)(base + 30*MB + 65536);

  cvtx_kernel<<<256, 256, 0, stream>>>(Wq, Wk, Wv, x, wh, wl, xpart);
  qkv_mfma<<<dim3(128,12), 256, 0, stream>>>(x, wh, wl, bq, bk, bv,
                                             qh, ql, kh, kl, vt);
  attn_kernel<<<dim3(128,16), 1024, 0, stream>>>(qh, ql, kh, kl, vt, atth, attl);
  gate_mprep_kernel<<<dim3(16,4), 256, 0, stream>>>(xpart, Wg, bg, Wgp, bgp,
                                                    Wd, bd, Wo, bo, mt_h, mt_l, bo_b);
  out_mfma<<<dim3(32,4,4), 256, 0, stream>>>(atth, attl, mt_h, mt_l, bo_b, (float*)d_out);
}